// Round 1
// baseline (1397.578 us; speedup 1.0000x reference)
//
#include <hip/hip_runtime.h>
#include <hip/hip_bf16.h>

#define BM_ 128   // B*M
#define T_  256
#define C_  512
#define NH  8
#define DH  64
#define KC  32

__device__ __forceinline__ float elu1(float v){ return v > 0.f ? v + 1.f : __expf(v); }

// Fused projection GEMM: computes a 64(t) x 128(d) tile of elu(x@W^T + b)+1.
// MODE 0 (K pass): emits krow (per-head row sums, complete per block) and
//                  atomically accumulates ksum[d] over t.
// MODE 1 (Q pass): dots each q row-segment with ksum and atomically
//                  accumulates the z-denominator per (head, t).
template<int MODE>
__global__ __launch_bounds__(256) void proj_kernel(
    const float* __restrict__ x, const float* __restrict__ W, const float* __restrict__ bias,
    float* __restrict__ krow, float* __restrict__ ksum,
    const float* __restrict__ ksum_in, float* __restrict__ zden)
{
  const int bm = blockIdx.x, tt = blockIdx.y, dt = blockIdx.z;
  const int tid = threadIdx.x;
  const int tx = tid & 15, ty = tid >> 4;

  __shared__ float xs[64][KC + 1];
  __shared__ float wsb[128][KC + 1];

  float acc[4][8];
#pragma unroll
  for (int i = 0; i < 4; i++)
#pragma unroll
    for (int j = 0; j < 8; j++) acc[i][j] = 0.f;

  const float* xbase = x + ((size_t)bm * T_ + tt * 64) * C_;
  const float* wbase = W + (size_t)dt * 128 * C_;

  for (int kc = 0; kc < C_; kc += KC) {
#pragma unroll
    for (int p = 0; p < 2; p++) {
      int idx = tid + p * 256;           // over [64][8] float4
      int r = idx >> 3, c4 = (idx & 7) * 4;
      float4 v = *reinterpret_cast<const float4*>(xbase + (size_t)r * C_ + kc + c4);
      xs[r][c4 + 0] = v.x; xs[r][c4 + 1] = v.y; xs[r][c4 + 2] = v.z; xs[r][c4 + 3] = v.w;
    }
#pragma unroll
    for (int p = 0; p < 4; p++) {
      int idx = tid + p * 256;           // over [128][8] float4
      int r = idx >> 3, c4 = (idx & 7) * 4;
      float4 v = *reinterpret_cast<const float4*>(wbase + (size_t)r * C_ + kc + c4);
      wsb[r][c4 + 0] = v.x; wsb[r][c4 + 1] = v.y; wsb[r][c4 + 2] = v.z; wsb[r][c4 + 3] = v.w;
    }
    __syncthreads();
#pragma unroll
    for (int k = 0; k < KC; k++) {
      float a0 = xs[ty * 4 + 0][k], a1 = xs[ty * 4 + 1][k];
      float a2 = xs[ty * 4 + 2][k], a3 = xs[ty * 4 + 3][k];
      float b[8];
#pragma unroll
      for (int j = 0; j < 8; j++) b[j] = wsb[tx + j * 16][k];   // stride-16 cols: conflict-free
#pragma unroll
      for (int j = 0; j < 8; j++) {
        acc[0][j] = fmaf(a0, b[j], acc[0][j]);
        acc[1][j] = fmaf(a1, b[j], acc[1][j]);
        acc[2][j] = fmaf(a2, b[j], acc[2][j]);
        acc[3][j] = fmaf(a3, b[j], acc[3][j]);
      }
    }
    __syncthreads();
  }

  float bj[8];
#pragma unroll
  for (int j = 0; j < 8; j++) bj[j] = bias[dt * 128 + tx + j * 16];

  if (MODE == 0) {
#pragma unroll
    for (int i = 0; i < 4; i++)
#pragma unroll
      for (int j = 0; j < 8; j++) acc[i][j] = elu1(acc[i][j] + bj[j]);
    // krow: per-head (64-col) row sums; cols tx+j*16, j<4 -> head dt*2, j>=4 -> dt*2+1
#pragma unroll
    for (int i = 0; i < 4; i++) {
      float rs0 = acc[i][0] + acc[i][1] + acc[i][2] + acc[i][3];
      float rs1 = acc[i][4] + acc[i][5] + acc[i][6] + acc[i][7];
#pragma unroll
      for (int m = 1; m < 16; m <<= 1) { rs0 += __shfl_xor(rs0, m); rs1 += __shfl_xor(rs1, m); }
      if (tx == 0) {
        int t = tt * 64 + ty * 4 + i;
        krow[((size_t)bm * NH + dt * 2    ) * T_ + t] = rs0;
        krow[((size_t)bm * NH + dt * 2 + 1) * T_ + t] = rs1;
      }
    }
    // ksum: reduce over the block's 64 rows (4 per thread, x4 ty within wave, x4 waves atomic)
#pragma unroll
    for (int j = 0; j < 8; j++) {
      float cs = acc[0][j] + acc[1][j] + acc[2][j] + acc[3][j];
      cs += __shfl_xor(cs, 16); cs += __shfl_xor(cs, 32);
      if ((ty & 3) == 0) atomicAdd(&ksum[(size_t)bm * C_ + dt * 128 + tx + j * 16], cs);
    }
  } else {
    float ks[8];
#pragma unroll
    for (int j = 0; j < 8; j++) ks[j] = ksum_in[(size_t)bm * C_ + dt * 128 + tx + j * 16];
#pragma unroll
    for (int i = 0; i < 4; i++) {
      float z0 = 0.f, z1 = 0.f;
#pragma unroll
      for (int j = 0; j < 4; j++) z0 = fmaf(elu1(acc[i][j] + bj[j]), ks[j], z0);
#pragma unroll
      for (int j = 4; j < 8; j++) z1 = fmaf(elu1(acc[i][j] + bj[j]), ks[j], z1);
#pragma unroll
      for (int m = 1; m < 16; m <<= 1) { z0 += __shfl_xor(z0, m); z1 += __shfl_xor(z1, m); }
      if (tx == 0) {
        int t = tt * 64 + ty * 4 + i;
        atomicAdd(&zden[((size_t)bm * NH + dt * 2    ) * T_ + t], z0);
        atomicAdd(&zden[((size_t)bm * NH + dt * 2 + 1) * T_ + t], z1);
      }
    }
  }
}

// xk_n[c] = sum_t krow_n[t] * x[bm,t,c]; also srow_n = sum_t krow_n[t].
__global__ __launch_bounds__(256) void xk_kernel(
    const float* __restrict__ x, const float* __restrict__ krow,
    float* __restrict__ xk, float* __restrict__ srow)
{
  const int bm = blockIdx.x, tid = threadIdx.x;
  __shared__ float krs[NH * T_];
#pragma unroll
  for (int p = 0; p < 8; p++) krs[tid + p * 256] = krow[(size_t)bm * NH * T_ + tid + p * 256];
  __syncthreads();
  float a0[8], a1[8], sr[8];
#pragma unroll
  for (int n = 0; n < 8; n++) { a0[n] = 0.f; a1[n] = 0.f; sr[n] = 0.f; }
  const float* xb = x + (size_t)bm * T_ * C_;
  for (int t = 0; t < T_; t++) {
    float x0 = xb[(size_t)t * C_ + tid];
    float x1 = xb[(size_t)t * C_ + 256 + tid];
#pragma unroll
    for (int n = 0; n < 8; n++) {
      float kr = krs[n * T_ + t];
      a0[n] = fmaf(kr, x0, a0[n]);
      a1[n] = fmaf(kr, x1, a1[n]);
      sr[n] += kr;
    }
  }
#pragma unroll
  for (int n = 0; n < 8; n++) {
    xk[((size_t)bm * NH + n) * C_ + tid]       = a0[n];
    xk[((size_t)bm * NH + n) * C_ + 256 + tid] = a1[n];
  }
  if (tid == 0) {
#pragma unroll
    for (int n = 0; n < 8; n++) srow[bm * NH + n] = sr[n] * 0.125f * 8.f; // = sr[n]
  }
}

// colsum_n[e] = Wv[n*64+e,:].xk_n + srow_n*bv[n*64+e];  w_n[c'] = sum_e colsum_n[e]*Wp[c',n*64+e]
__global__ __launch_bounds__(256) void small_kernel(
    const float* __restrict__ xk, const float* __restrict__ srow,
    const float* __restrict__ Wv, const float* __restrict__ bv,
    const float* __restrict__ Wp, float* __restrict__ wbuf)
{
  const int bm = blockIdx.x, tid = threadIdx.x;
  __shared__ float xs[NH * C_];
  __shared__ float cs[NH * DH];
#pragma unroll
  for (int p = 0; p < 16; p++) xs[tid + p * 256] = xk[(size_t)bm * NH * C_ + tid + p * 256];
  __syncthreads();
#pragma unroll
  for (int p = 0; p < 2; p++) {
    int o = tid + p * 256;
    int h = o >> 6, e = o & 63;
    const float* wv = Wv + (size_t)(h * DH + e) * C_;
    const float* xh = xs + h * C_;
    float s = srow[bm * NH + h] * bv[h * DH + e];
    for (int c = 0; c < C_; c += 4) {
      float4 w4 = *reinterpret_cast<const float4*>(wv + c);
      s += w4.x * xh[c] + w4.y * xh[c + 1] + w4.z * xh[c + 2] + w4.w * xh[c + 3];
    }
    cs[o] = s;
  }
  __syncthreads();
#pragma unroll
  for (int h = 0; h < NH; h++) {
#pragma unroll
    for (int p = 0; p < 2; p++) {
      int cp = tid + p * 256;
      const float* wp = Wp + (size_t)cp * C_ + h * DH;
      const float* ch = cs + h * DH;
      float s = 0.f;
#pragma unroll
      for (int e = 0; e < DH; e += 4) {
        float4 w4 = *reinterpret_cast<const float4*>(wp + e);
        s += w4.x * ch[e] + w4.y * ch[e + 1] + w4.z * ch[e + 2] + w4.w * ch[e + 3];
      }
      wbuf[((size_t)bm * NH + h) * C_ + cp] = s;
    }
  }
}

// out[bm,t,c'] = sum_n z_n[t]*w_n[c'] + bp[c'],  z = 1/(zden+eps)
__global__ __launch_bounds__(256) void out_kernel(
    const float* __restrict__ zden, const float* __restrict__ wbuf,
    const float* __restrict__ bp, float* __restrict__ out)
{
  const int bm = blockIdx.x, tt = blockIdx.y, tid = threadIdx.x;
  __shared__ float zs[NH][64];
#pragma unroll
  for (int p = 0; p < 2; p++) {
    int idx = tid + p * 256;
    int n = idx >> 6, t = idx & 63;
    zs[n][t] = 1.f / (zden[((size_t)bm * NH + n) * T_ + tt * 64 + t] + 1e-6f);
  }
  float2 wv[8];
  const int c2 = tid * 2;
#pragma unroll
  for (int n = 0; n < 8; n++)
    wv[n] = *reinterpret_cast<const float2*>(wbuf + ((size_t)bm * NH + n) * C_ + c2);
  float2 bpv = *reinterpret_cast<const float2*>(bp + c2);
  __syncthreads();
  float* ob = out + ((size_t)bm * T_ + tt * 64) * C_;
  for (int t = 0; t < 64; t++) {
    float o0 = bpv.x, o1 = bpv.y;
#pragma unroll
    for (int n = 0; n < 8; n++) { float z = zs[n][t]; o0 = fmaf(z, wv[n].x, o0); o1 = fmaf(z, wv[n].y, o1); }
    *reinterpret_cast<float2*>(ob + (size_t)t * C_ + c2) = make_float2(o0, o1);
  }
}

extern "C" void kernel_launch(void* const* d_in, const int* in_sizes, int n_in,
                              void* d_out, int out_size, void* d_ws, size_t ws_size,
                              hipStream_t stream)
{
  const float* x  = (const float*)d_in[0];
  const float* Wq = (const float*)d_in[1];
  const float* bq = (const float*)d_in[2];
  const float* Wk = (const float*)d_in[3];
  const float* bk = (const float*)d_in[4];
  const float* Wv = (const float*)d_in[5];
  const float* bv = (const float*)d_in[6];
  const float* Wp = (const float*)d_in[7];
  const float* bp = (const float*)d_in[8];
  float* out = (float*)d_out;

  float* ws   = (float*)d_ws;
  float* zden = ws;                        // 128*8*256 = 262144
  float* ksum = zden + 262144;             // 128*8*64  = 65536
  float* krow = ksum + 65536;              // 128*8*256 = 262144
  float* srow = krow + 262144;             // 128*8     = 1024
  float* xk   = srow + 1024;               // 128*8*512 = 524288
  float* wbuf = xk + 524288;               // 128*8*512 = 524288

  // zden and ksum are atomically accumulated -> zero them every call
  hipMemsetAsync(zden, 0, (262144 + 65536) * sizeof(float), stream);

  dim3 g(BM_, 4, 4);
  proj_kernel<0><<<g, 256, 0, stream>>>(x, Wk, bk, krow, ksum, nullptr, nullptr);
  xk_kernel<<<BM_, 256, 0, stream>>>(x, krow, xk, srow);
  small_kernel<<<BM_, 256, 0, stream>>>(xk, srow, Wv, bv, Wp, wbuf);
  proj_kernel<1><<<g, 256, 0, stream>>>(x, Wq, bq, nullptr, nullptr, ksum, zden);
  out_kernel<<<dim3(BM_, 4), 256, 0, stream>>>(zden, wbuf, bp, out);
}

// Round 2
// 192.101 us; speedup vs baseline: 7.2752x; 7.2752x over previous
//
#include <hip/hip_runtime.h>
#include <hip/hip_bf16.h>

#define BM_ 128   // B*M
#define T_  256
#define C_  512
#define NH  8
#define DH  64

typedef __bf16 bf16;
typedef __attribute__((ext_vector_type(8))) __bf16 bf16x8;
typedef __attribute__((ext_vector_type(4))) float f32x4;

__device__ __forceinline__ float elu1(float v){ return v > 0.f ? v + 1.f : __expf(v); }

__device__ __forceinline__ unsigned short f2bf(float f){
  unsigned u = __float_as_uint(f);
  u += 0x7fffu + ((u >> 16) & 1u);
  return (unsigned short)(u >> 16);
}

#define GLOAD16(gptr, lptr) __builtin_amdgcn_global_load_lds( \
  (const __attribute__((address_space(1))) void*)(gptr), \
  (__attribute__((address_space(3))) void*)(lptr), 16, 0, 0)

// fp32 -> bf16 (RNE), vectorized float4 -> ushort4
__global__ __launch_bounds__(256) void cvt_kernel(const float* __restrict__ in,
                                                  unsigned short* __restrict__ out, int n4)
{
  int i = blockIdx.x * blockDim.x + threadIdx.x;
  int stride = gridDim.x * blockDim.x;
  for (; i < n4; i += stride) {
    float4 v = reinterpret_cast<const float4*>(in)[i];
    ushort4 o;
    o.x = f2bf(v.x); o.y = f2bf(v.y); o.z = f2bf(v.z); o.w = f2bf(v.w);
    reinterpret_cast<ushort4*>(out)[i] = o;
  }
}

// Fused bf16 MFMA projection GEMM. A = xb [32768][512], Bw = W [512(n)][512(k)]
// (nn.Linear weight layout == B^T, rows are output features -> contiguous k).
// Tile 128(t) x 128(d), BK=32, 4 waves in 2x2, each wave 64x64 via 4x4 16x16x32 MFMAs.
// MODE 0 (K): out-of-core only reductions: krow[bm,head,t] (complete per wave),
//             ksum[bm,d] (atomic over t-tiles).
// MODE 1 (Q): zden[bm,head,t] = sum_d q[t,d]*ksum[d]  (complete per wave, direct store).
template<int MODE>
__global__ __launch_bounds__(256) void gemm_proj(
    const bf16* __restrict__ A, const bf16* __restrict__ Bw,
    const float* __restrict__ bias,
    float* __restrict__ krow, float* __restrict__ ksum,
    const float* __restrict__ ksum_in, float* __restrict__ zden)
{
  __shared__ bf16 As[128 * 32];
  __shared__ bf16 Bs[128 * 32];

  const int tid  = threadIdx.x;
  const int lane = tid & 63;
  const int wid  = tid >> 6;
  const int wm   = wid >> 1, wn = wid & 1;    // 2x2 wave grid
  const int tm   = blockIdx.x, tn = blockIdx.y;

  f32x4 acc[4][4];
#pragma unroll
  for (int i = 0; i < 4; i++)
#pragma unroll
    for (int j = 0; j < 4; j++) acc[i][j] = (f32x4){0.f, 0.f, 0.f, 0.f};

  const bf16* Ab = A  + (size_t)(tm * 128) * C_;
  const bf16* Bb = Bw + (size_t)(tn * 128) * C_;

  const int strow = tid >> 2;            // 0..63
  const int skoff = (tid & 3) * 8;       // 0,8,16,24 (bf16 elems)
  const int fr = lane & 15;              // frag row/col within 16
  const int fq = lane >> 4;              // k-group / row-quad
  const int fk = fq * 8;                 // k offset of this lane's 8 elems

  for (int kc = 0; kc < C_; kc += 32) {
    GLOAD16(Ab + (size_t)strow * C_ + kc + skoff,        As + strow * 32 + skoff);
    GLOAD16(Ab + (size_t)(strow + 64) * C_ + kc + skoff, As + (strow + 64) * 32 + skoff);
    GLOAD16(Bb + (size_t)strow * C_ + kc + skoff,        Bs + strow * 32 + skoff);
    GLOAD16(Bb + (size_t)(strow + 64) * C_ + kc + skoff, Bs + (strow + 64) * 32 + skoff);
    asm volatile("s_waitcnt vmcnt(0)" ::: "memory");
    __syncthreads();

    bf16x8 af[4], bfr[4];
#pragma unroll
    for (int i = 0; i < 4; i++)
      af[i] = *reinterpret_cast<const bf16x8*>(&As[(wm * 64 + i * 16 + fr) * 32 + fk]);
#pragma unroll
    for (int j = 0; j < 4; j++)
      bfr[j] = *reinterpret_cast<const bf16x8*>(&Bs[(wn * 64 + j * 16 + fr) * 32 + fk]);
#pragma unroll
    for (int i = 0; i < 4; i++)
#pragma unroll
      for (int j = 0; j < 4; j++)
        acc[i][j] = __builtin_amdgcn_mfma_f32_16x16x32_bf16(af[i], bfr[j], acc[i][j], 0, 0, 0);
    __syncthreads();
  }

  // ---- epilogue ----
  const int bm   = tm >> 1;                 // 128 rows never cross a bm slab
  const int head = tn * 2 + wn;             // each wave owns one complete head (64 cols)
  float bj[4];
#pragma unroll
  for (int j = 0; j < 4; j++) bj[j] = bias[tn * 128 + wn * 64 + j * 16 + fr];

  if (MODE == 0) {
    float cs[4] = {0.f, 0.f, 0.f, 0.f};     // column sums (this lane's 4 cols)
#pragma unroll
    for (int i = 0; i < 4; i++) {
#pragma unroll
      for (int r = 0; r < 4; r++) {
        float rs = 0.f;
#pragma unroll
        for (int j = 0; j < 4; j++) {
          float v = elu1(acc[i][j][r] + bj[j]);
          rs += v;
          cs[j] += v;
        }
        // row sum over the 16 fr-lanes
#pragma unroll
        for (int m = 1; m < 16; m <<= 1) rs += __shfl_xor(rs, m);
        if (fr == 0) {
          int grow = tm * 128 + wm * 64 + i * 16 + fq * 4 + r;
          krow[((size_t)bm * NH + head) * T_ + (grow & 255)] = rs;
        }
      }
    }
    // column sums: reduce over fq groups, then atomic over t-tiles/waves
#pragma unroll
    for (int j = 0; j < 4; j++) {
      cs[j] += __shfl_xor(cs[j], 16);
      cs[j] += __shfl_xor(cs[j], 32);
      if (fq == 0)
        atomicAdd(&ksum[(size_t)bm * C_ + tn * 128 + wn * 64 + j * 16 + fr], cs[j]);
    }
  } else {
    float ks[4];
#pragma unroll
    for (int j = 0; j < 4; j++) ks[j] = ksum_in[(size_t)bm * C_ + tn * 128 + wn * 64 + j * 16 + fr];
#pragma unroll
    for (int i = 0; i < 4; i++) {
#pragma unroll
      for (int r = 0; r < 4; r++) {
        float zs = 0.f;
#pragma unroll
        for (int j = 0; j < 4; j++) zs = fmaf(elu1(acc[i][j][r] + bj[j]), ks[j], zs);
#pragma unroll
        for (int m = 1; m < 16; m <<= 1) zs += __shfl_xor(zs, m);
        if (fr == 0) {
          int grow = tm * 128 + wm * 64 + i * 16 + fq * 4 + r;
          zden[((size_t)bm * NH + head) * T_ + (grow & 255)] = zs;
        }
      }
    }
  }
}

// xk_n[c] = sum_t krow_n[t] * x[bm,t,c]; srow_n = sum_t krow_n[t]. fp32 for accuracy.
__global__ __launch_bounds__(256) void xk_kernel(
    const float* __restrict__ x, const float* __restrict__ krow,
    float* __restrict__ xk, float* __restrict__ srow)
{
  const int bm = blockIdx.x, half = blockIdx.y, tid = threadIdx.x;
  __shared__ float krs[NH * T_];
#pragma unroll
  for (int p = 0; p < 8; p++) krs[tid + p * 256] = krow[(size_t)bm * NH * T_ + tid + p * 256];
  __syncthreads();
  float a[8];
#pragma unroll
  for (int n = 0; n < 8; n++) a[n] = 0.f;
  const float* xb = x + (size_t)bm * T_ * C_ + half * 256 + tid;
  for (int t = 0; t < T_; t++) {
    float xv = xb[(size_t)t * C_];
#pragma unroll
    for (int n = 0; n < 8; n++) a[n] = fmaf(krs[n * T_ + t], xv, a[n]);
  }
#pragma unroll
  for (int n = 0; n < 8; n++)
    xk[((size_t)bm * NH + n) * C_ + half * 256 + tid] = a[n];
  if (half == 0 && tid < 8) {
    float s = 0.f;
    for (int t = 0; t < T_; t++) s += krs[tid * T_ + t];
    srow[bm * NH + tid] = s;
  }
}

// colsum_n[e] = Wv[n*64+e,:].xk_n + srow_n*bv[n*64+e];  w_n[c'] = sum_e colsum_n[e]*Wp[c',n*64+e]
__global__ __launch_bounds__(256) void small_kernel(
    const float* __restrict__ xk, const float* __restrict__ srow,
    const float* __restrict__ Wv, const float* __restrict__ bv,
    const float* __restrict__ Wp, float* __restrict__ wbuf)
{
  const int bm = blockIdx.x, tid = threadIdx.x;
  __shared__ float xs[NH * C_];
  __shared__ float cs[NH * DH];
#pragma unroll
  for (int p = 0; p < 16; p++) xs[tid + p * 256] = xk[(size_t)bm * NH * C_ + tid + p * 256];
  __syncthreads();
#pragma unroll
  for (int p = 0; p < 2; p++) {
    int o = tid + p * 256;
    int h = o >> 6, e = o & 63;
    const float* wv = Wv + (size_t)(h * DH + e) * C_;
    const float* xh = xs + h * C_;
    float s = srow[bm * NH + h] * bv[h * DH + e];
    for (int c = 0; c < C_; c += 4) {
      float4 w4 = *reinterpret_cast<const float4*>(wv + c);
      s += w4.x * xh[c] + w4.y * xh[c + 1] + w4.z * xh[c + 2] + w4.w * xh[c + 3];
    }
    cs[o] = s;
  }
  __syncthreads();
#pragma unroll
  for (int h = 0; h < NH; h++) {
#pragma unroll
    for (int p = 0; p < 2; p++) {
      int cp = tid + p * 256;
      const float* wp = Wp + (size_t)cp * C_ + h * DH;
      const float* ch = cs + h * DH;
      float s = 0.f;
#pragma unroll
      for (int e = 0; e < DH; e += 4) {
        float4 w4 = *reinterpret_cast<const float4*>(wp + e);
        s += w4.x * ch[e] + w4.y * ch[e + 1] + w4.z * ch[e + 2] + w4.w * ch[e + 3];
      }
      wbuf[((size_t)bm * NH + h) * C_ + cp] = s;
    }
  }
}

// out[bm,t,c'] = sum_n z_n[t]*w_n[c'] + bp[c'],  z = 1/(zden+eps)
__global__ __launch_bounds__(256) void out_kernel(
    const float* __restrict__ zden, const float* __restrict__ wbuf,
    const float* __restrict__ bp, float* __restrict__ out)
{
  const int bm = blockIdx.x, tt = blockIdx.y, tid = threadIdx.x;
  __shared__ float zs[NH][64];
#pragma unroll
  for (int p = 0; p < 2; p++) {
    int idx = tid + p * 256;
    int n = idx >> 6, t = idx & 63;
    zs[n][t] = 1.f / (zden[((size_t)bm * NH + n) * T_ + tt * 64 + t] + 1e-6f);
  }
  float2 wv[8];
  const int c2 = tid * 2;
#pragma unroll
  for (int n = 0; n < 8; n++)
    wv[n] = *reinterpret_cast<const float2*>(wbuf + ((size_t)bm * NH + n) * C_ + c2);
  float2 bpv = *reinterpret_cast<const float2*>(bp + c2);
  __syncthreads();
  float* ob = out + ((size_t)bm * T_ + tt * 64) * C_;
  for (int t = 0; t < 64; t++) {
    float o0 = bpv.x, o1 = bpv.y;
#pragma unroll
    for (int n = 0; n < 8; n++) { float z = zs[n][t]; o0 = fmaf(z, wv[n].x, o0); o1 = fmaf(z, wv[n].y, o1); }
    *reinterpret_cast<float2*>(ob + (size_t)t * C_ + c2) = make_float2(o0, o1);
  }
}

extern "C" void kernel_launch(void* const* d_in, const int* in_sizes, int n_in,
                              void* d_out, int out_size, void* d_ws, size_t ws_size,
                              hipStream_t stream)
{
  const float* x  = (const float*)d_in[0];
  const float* Wq = (const float*)d_in[1];
  const float* bq = (const float*)d_in[2];
  const float* Wk = (const float*)d_in[3];
  const float* bk = (const float*)d_in[4];
  const float* Wv = (const float*)d_in[5];
  const float* bv = (const float*)d_in[6];
  const float* Wp = (const float*)d_in[7];
  const float* bp = (const float*)d_in[8];
  float* out = (float*)d_out;

  float* ws   = (float*)d_ws;
  float* zden = ws;                        // 128*8*256 = 262144 f
  float* ksum = zden + 262144;             // 128*512   = 65536 f
  float* krow = ksum + 65536;              // 128*8*256 = 262144 f
  float* srow = krow + 262144;             // 1024 f
  float* xk   = srow + 1024;               // 524288 f
  float* wbuf = xk + 524288;               // 524288 f
  unsigned short* xb  = (unsigned short*)(wbuf + 524288);  // 16.7M bf16
  unsigned short* wkb = xb + 16777216;                      // 262144 bf16
  unsigned short* wqb = wkb + 262144;                       // 262144 bf16

  // ksum is atomically accumulated -> zero every call
  hipMemsetAsync(ksum, 0, 65536 * sizeof(float), stream);

  cvt_kernel<<<2048, 256, 0, stream>>>(x,  xb,  16777216 / 4);
  cvt_kernel<<<256,  256, 0, stream>>>(Wk, wkb, 262144 / 4);
  cvt_kernel<<<256,  256, 0, stream>>>(Wq, wqb, 262144 / 4);

  dim3 g(256, 4);
  gemm_proj<0><<<g, 256, 0, stream>>>((const bf16*)xb, (const bf16*)wkb, bk,
                                      krow, ksum, nullptr, nullptr);
  xk_kernel<<<dim3(BM_, 2), 256, 0, stream>>>(x, krow, xk, srow);
  small_kernel<<<BM_, 256, 0, stream>>>(xk, srow, Wv, bv, Wp, wbuf);
  gemm_proj<1><<<g, 256, 0, stream>>>((const bf16*)xb, (const bf16*)wqb, bq,
                                      nullptr, nullptr, ksum, zden);
  out_kernel<<<dim3(BM_, 4), 256, 0, stream>>>(zden, wbuf, bp, out);
}

// Round 3
// 162.895 us; speedup vs baseline: 8.5796x; 1.1793x over previous
//
#include <hip/hip_runtime.h>
#include <hip/hip_bf16.h>

#define BM_ 128   // B*M
#define T_  256
#define C_  512
#define NH  8
#define DH  64

typedef __bf16 bf16;
typedef __attribute__((ext_vector_type(8))) __bf16 bf16x8;
typedef __attribute__((ext_vector_type(4))) float f32x4;

__device__ __forceinline__ float elu1(float v){ return v > 0.f ? v + 1.f : __expf(v); }

__device__ __forceinline__ unsigned short f2bf(float f){
  unsigned u = __float_as_uint(f);
  u += 0x7fffu + ((u >> 16) & 1u);
  return (unsigned short)(u >> 16);
}

__device__ __forceinline__ float bf2f(unsigned short b){
  return __uint_as_float(((unsigned)b) << 16);
}

#define GLOAD16(gptr, lptr) __builtin_amdgcn_global_load_lds( \
  (const __attribute__((address_space(1))) void*)(gptr), \
  (__attribute__((address_space(3))) void*)(lptr), 16, 0, 0)

// fp32 -> bf16 (RNE), vectorized float4 -> ushort4
__global__ __launch_bounds__(256) void cvt_kernel(const float* __restrict__ in,
                                                  unsigned short* __restrict__ out, int n4)
{
  int i = blockIdx.x * blockDim.x + threadIdx.x;
  int stride = gridDim.x * blockDim.x;
  for (; i < n4; i += stride) {
    float4 v = reinterpret_cast<const float4*>(in)[i];
    ushort4 o;
    o.x = f2bf(v.x); o.y = f2bf(v.y); o.z = f2bf(v.z); o.w = f2bf(v.w);
    reinterpret_cast<ushort4*>(out)[i] = o;
  }
}

// Fused bf16 MFMA projection GEMM (see round-2 notes). 128x128 tile, BK=32.
template<int MODE>
__global__ __launch_bounds__(256) void gemm_proj(
    const bf16* __restrict__ A, const bf16* __restrict__ Bw,
    const float* __restrict__ bias,
    float* __restrict__ krow, float* __restrict__ ksum,
    const float* __restrict__ ksum_in, float* __restrict__ zden)
{
  __shared__ bf16 As[128 * 32];
  __shared__ bf16 Bs[128 * 32];

  const int tid  = threadIdx.x;
  const int lane = tid & 63;
  const int wid  = tid >> 6;
  const int wm   = wid >> 1, wn = wid & 1;
  const int tm   = blockIdx.x, tn = blockIdx.y;

  f32x4 acc[4][4];
#pragma unroll
  for (int i = 0; i < 4; i++)
#pragma unroll
    for (int j = 0; j < 4; j++) acc[i][j] = (f32x4){0.f, 0.f, 0.f, 0.f};

  const bf16* Ab = A  + (size_t)(tm * 128) * C_;
  const bf16* Bb = Bw + (size_t)(tn * 128) * C_;

  const int strow = tid >> 2;
  const int skoff = (tid & 3) * 8;
  const int fr = lane & 15;
  const int fq = lane >> 4;
  const int fk = fq * 8;

  for (int kc = 0; kc < C_; kc += 32) {
    GLOAD16(Ab + (size_t)strow * C_ + kc + skoff,        As + strow * 32 + skoff);
    GLOAD16(Ab + (size_t)(strow + 64) * C_ + kc + skoff, As + (strow + 64) * 32 + skoff);
    GLOAD16(Bb + (size_t)strow * C_ + kc + skoff,        Bs + strow * 32 + skoff);
    GLOAD16(Bb + (size_t)(strow + 64) * C_ + kc + skoff, Bs + (strow + 64) * 32 + skoff);
    asm volatile("s_waitcnt vmcnt(0)" ::: "memory");
    __syncthreads();

    bf16x8 af[4], bfr[4];
#pragma unroll
    for (int i = 0; i < 4; i++)
      af[i] = *reinterpret_cast<const bf16x8*>(&As[(wm * 64 + i * 16 + fr) * 32 + fk]);
#pragma unroll
    for (int j = 0; j < 4; j++)
      bfr[j] = *reinterpret_cast<const bf16x8*>(&Bs[(wn * 64 + j * 16 + fr) * 32 + fk]);
#pragma unroll
    for (int i = 0; i < 4; i++)
#pragma unroll
      for (int j = 0; j < 4; j++)
        acc[i][j] = __builtin_amdgcn_mfma_f32_16x16x32_bf16(af[i], bfr[j], acc[i][j], 0, 0, 0);
    __syncthreads();
  }

  const int bm   = tm >> 1;
  const int head = tn * 2 + wn;
  float bj[4];
#pragma unroll
  for (int j = 0; j < 4; j++) bj[j] = bias[tn * 128 + wn * 64 + j * 16 + fr];

  if (MODE == 0) {
    float cs[4] = {0.f, 0.f, 0.f, 0.f};
#pragma unroll
    for (int i = 0; i < 4; i++) {
#pragma unroll
      for (int r = 0; r < 4; r++) {
        float rs = 0.f;
#pragma unroll
        for (int j = 0; j < 4; j++) {
          float v = elu1(acc[i][j][r] + bj[j]);
          rs += v;
          cs[j] += v;
        }
#pragma unroll
        for (int m = 1; m < 16; m <<= 1) rs += __shfl_xor(rs, m);
        if (fr == 0) {
          int grow = tm * 128 + wm * 64 + i * 16 + fq * 4 + r;
          krow[((size_t)bm * NH + head) * T_ + (grow & 255)] = rs;
        }
      }
    }
#pragma unroll
    for (int j = 0; j < 4; j++) {
      cs[j] += __shfl_xor(cs[j], 16);
      cs[j] += __shfl_xor(cs[j], 32);
      if (fq == 0)
        atomicAdd(&ksum[(size_t)bm * C_ + tn * 128 + wn * 64 + j * 16 + fr], cs[j]);
    }
  } else {
    float ks[4];
#pragma unroll
    for (int j = 0; j < 4; j++) ks[j] = ksum_in[(size_t)bm * C_ + tn * 128 + wn * 64 + j * 16 + fr];
#pragma unroll
    for (int i = 0; i < 4; i++) {
#pragma unroll
      for (int r = 0; r < 4; r++) {
        float zs = 0.f;
#pragma unroll
        for (int j = 0; j < 4; j++) zs = fmaf(elu1(acc[i][j][r] + bj[j]), ks[j], zs);
#pragma unroll
        for (int m = 1; m < 16; m <<= 1) zs += __shfl_xor(zs, m);
        if (fr == 0) {
          int grow = tm * 128 + wm * 64 + i * 16 + fq * 4 + r;
          zden[((size_t)bm * NH + head) * T_ + (grow & 255)] = zs;
        }
      }
    }
  }
}

// xk_n[c] = sum_t krow_n[t] * x[bm,t,c]; srow_n = sum_t krow_n[t]. bf16 x, fp32 accum.
__global__ __launch_bounds__(256) void xk_kernel(
    const unsigned short* __restrict__ xb, const float* __restrict__ krow,
    float* __restrict__ xk, float* __restrict__ srow)
{
  const int bm = blockIdx.x, tid = threadIdx.x;
  __shared__ float krs[NH * T_];
#pragma unroll
  for (int p = 0; p < 8; p++) krs[tid + p * 256] = krow[(size_t)bm * NH * T_ + tid + p * 256];
  __syncthreads();
  float a0[8], a1[8];
#pragma unroll
  for (int n = 0; n < 8; n++) { a0[n] = 0.f; a1[n] = 0.f; }
  const unsigned short* xp = xb + (size_t)bm * T_ * C_ + tid * 2;
  for (int t = 0; t < T_; t++) {
    ushort2 u = *reinterpret_cast<const ushort2*>(xp + (size_t)t * C_);
    float x0 = bf2f(u.x), x1 = bf2f(u.y);
#pragma unroll
    for (int n = 0; n < 8; n++) {
      float kr = krs[n * T_ + t];
      a0[n] = fmaf(kr, x0, a0[n]);
      a1[n] = fmaf(kr, x1, a1[n]);
    }
  }
#pragma unroll
  for (int n = 0; n < 8; n++)
    *reinterpret_cast<float2*>(&xk[((size_t)bm * NH + n) * C_ + tid * 2]) = make_float2(a0[n], a1[n]);
  if (tid < 8) {
    float s = 0.f;
    for (int t = 0; t < T_; t++) s += krs[tid * T_ + t];
    srow[bm * NH + tid] = s;
  }
}

// colsum[bm,h,e] = Wv[h*64+e,:] . xk[bm,h,:] + srow[bm,h]*bv[h*64+e]
// grid (16 bm-tiles of 8, 8 heads); Wv row streamed once per 8 bms.
__global__ __launch_bounds__(256) void colsum_kernel(
    const float* __restrict__ xk, const float* __restrict__ srow,
    const float* __restrict__ Wv, const float* __restrict__ bv,
    float* __restrict__ cs_g)
{
  const int bm0 = blockIdx.x * 8, h = blockIdx.y, tid = threadIdx.x;
  __shared__ float4 xs4[8][128];
#pragma unroll
  for (int p = 0; p < 4; p++) {
    int idx = tid + p * 256;
    int bmr = idx >> 7, c4 = idx & 127;
    xs4[bmr][c4] = *reinterpret_cast<const float4*>(
        xk + ((size_t)(bm0 + bmr) * NH + h) * C_ + c4 * 4);
  }
  __syncthreads();
  const int e = tid & 63, bs = tid >> 6;   // bs uniform per wave -> broadcast LDS reads
  const float4* wv4 = reinterpret_cast<const float4*>(Wv + (size_t)(h * DH + e) * C_);
  float acc0 = 0.f, acc1 = 0.f;
#pragma unroll 4
  for (int c4 = 0; c4 < 128; c4++) {
    float4 w = wv4[c4];
    float4 a = xs4[bs * 2][c4];
    float4 b = xs4[bs * 2 + 1][c4];
    acc0 += w.x * a.x + w.y * a.y + w.z * a.z + w.w * a.w;
    acc1 += w.x * b.x + w.y * b.y + w.z * b.z + w.w * b.w;
  }
  float bve = bv[h * DH + e];
  int bmA = bm0 + bs * 2, bmB = bmA + 1;
  cs_g[((size_t)bmA * NH + h) * DH + e] = acc0 + srow[bmA * NH + h] * bve;
  cs_g[((size_t)bmB * NH + h) * DH + e] = acc1 + srow[bmB * NH + h] * bve;
}

// wbuf[bm,h,cp] = sum_e cs[bm,h,e] * Wp[cp, h*64+e]
// grid (2 cp-tiles, 8 heads, 8 bm-tiles of 16); Wp row held in registers for 16 bms.
__global__ __launch_bounds__(256) void wbuf_kernel(
    const float* __restrict__ cs_g, const float* __restrict__ Wp,
    float* __restrict__ wbuf)
{
  const int cpt = blockIdx.x, h = blockIdx.y, bm0 = blockIdx.z * 16;
  const int tid = threadIdx.x;
  __shared__ float4 csL4[16][16];
#pragma unroll
  for (int p = 0; p < 1; p++) {
    int idx = tid;   // 256 = 16 bms x 16 float4
    int bmr = idx >> 4, e4 = idx & 15;
    csL4[bmr][e4] = *reinterpret_cast<const float4*>(
        cs_g + ((size_t)(bm0 + bmr) * NH + h) * DH + e4 * 4);
  }
  __syncthreads();
  const int cp = cpt * 256 + tid;
  float4 wp[16];
  const float4* wpr = reinterpret_cast<const float4*>(Wp + (size_t)cp * C_ + h * DH);
#pragma unroll
  for (int e4 = 0; e4 < 16; e4++) wp[e4] = wpr[e4];
#pragma unroll
  for (int bmr = 0; bmr < 16; bmr++) {
    float acc = 0.f;
#pragma unroll
    for (int e4 = 0; e4 < 16; e4++) {
      float4 c = csL4[bmr][e4];
      acc += wp[e4].x * c.x + wp[e4].y * c.y + wp[e4].z * c.z + wp[e4].w * c.w;
    }
    wbuf[((size_t)(bm0 + bmr) * NH + h) * C_ + cp] = acc;
  }
}

// out[bm,t,c'] = sum_n z_n[t]*w_n[c'] + bp[c'],  z = 1/(zden+eps)
__global__ __launch_bounds__(256) void out_kernel(
    const float* __restrict__ zden, const float* __restrict__ wbuf,
    const float* __restrict__ bp, float* __restrict__ out)
{
  const int bm = blockIdx.x, tt = blockIdx.y, tid = threadIdx.x;
  __shared__ float zs[NH][64];
#pragma unroll
  for (int p = 0; p < 2; p++) {
    int idx = tid + p * 256;
    int n = idx >> 6, t = idx & 63;
    zs[n][t] = 1.f / (zden[((size_t)bm * NH + n) * T_ + tt * 64 + t] + 1e-6f);
  }
  float2 wv[8];
  const int c2 = tid * 2;
#pragma unroll
  for (int n = 0; n < 8; n++)
    wv[n] = *reinterpret_cast<const float2*>(wbuf + ((size_t)bm * NH + n) * C_ + c2);
  float2 bpv = *reinterpret_cast<const float2*>(bp + c2);
  __syncthreads();
  float* ob = out + ((size_t)bm * T_ + tt * 64) * C_;
  for (int t = 0; t < 64; t++) {
    float o0 = bpv.x, o1 = bpv.y;
#pragma unroll
    for (int n = 0; n < 8; n++) { float z = zs[n][t]; o0 = fmaf(z, wv[n].x, o0); o1 = fmaf(z, wv[n].y, o1); }
    *reinterpret_cast<float2*>(ob + (size_t)t * C_ + c2) = make_float2(o0, o1);
  }
}

extern "C" void kernel_launch(void* const* d_in, const int* in_sizes, int n_in,
                              void* d_out, int out_size, void* d_ws, size_t ws_size,
                              hipStream_t stream)
{
  const float* x  = (const float*)d_in[0];
  const float* Wq = (const float*)d_in[1];
  const float* bq = (const float*)d_in[2];
  const float* Wk = (const float*)d_in[3];
  const float* bk = (const float*)d_in[4];
  const float* Wv = (const float*)d_in[5];
  const float* bv = (const float*)d_in[6];
  const float* Wp = (const float*)d_in[7];
  const float* bp = (const float*)d_in[8];
  float* out = (float*)d_out;

  float* ws   = (float*)d_ws;
  float* zden = ws;                        // 262144 f
  float* ksum = zden + 262144;             // 65536 f
  float* krow = ksum + 65536;              // 262144 f
  float* srow = krow + 262144;             // 1024 f
  float* xk   = srow + 1024;               // 524288 f
  float* cs   = xk + 524288;               // 65536 f (128*8*64)
  float* wbuf = cs + 65536;                // 524288 f
  unsigned short* xb  = (unsigned short*)(wbuf + 524288);  // 16.7M bf16
  unsigned short* wkb = xb + 16777216;
  unsigned short* wqb = wkb + 262144;

  hipMemsetAsync(ksum, 0, 65536 * sizeof(float), stream);

  cvt_kernel<<<2048, 256, 0, stream>>>(x,  xb,  16777216 / 4);
  cvt_kernel<<<256,  256, 0, stream>>>(Wk, wkb, 262144 / 4);
  cvt_kernel<<<256,  256, 0, stream>>>(Wq, wqb, 262144 / 4);

  dim3 g(256, 4);
  gemm_proj<0><<<g, 256, 0, stream>>>((const bf16*)xb, (const bf16*)wkb, bk,
                                      krow, ksum, nullptr, nullptr);
  xk_kernel<<<BM_, 256, 0, stream>>>(xb, krow, xk, srow);
  colsum_kernel<<<dim3(16, 8), 256, 0, stream>>>(xk, srow, Wv, bv, cs);
  wbuf_kernel<<<dim3(2, 8, 8), 256, 0, stream>>>(cs, Wp, wbuf);
  gemm_proj<1><<<g, 256, 0, stream>>>((const bf16*)xb, (const bf16*)wqb, bq,
                                      nullptr, nullptr, ksum, zden);
  out_kernel<<<dim3(BM_, 4), 256, 0, stream>>>(zden, wbuf, bp, out);
}

// Round 4
// 156.027 us; speedup vs baseline: 8.9573x; 1.0440x over previous
//
#include <hip/hip_runtime.h>
#include <hip/hip_bf16.h>

#define BM_ 128   // B*M
#define T_  256
#define C_  512
#define NH  8
#define DH  64

typedef __bf16 bf16;
typedef __attribute__((ext_vector_type(8))) __bf16 bf16x8;
typedef __attribute__((ext_vector_type(4))) float f32x4;

__device__ __forceinline__ float elu1(float v){ return v > 0.f ? v + 1.f : __expf(v); }

__device__ __forceinline__ unsigned short f2bf(float f){
  unsigned u = __float_as_uint(f);
  u += 0x7fffu + ((u >> 16) & 1u);
  return (unsigned short)(u >> 16);
}

__device__ __forceinline__ float bf2f(unsigned short b){
  return __uint_as_float(((unsigned)b) << 16);
}

#define GLOAD16(gptr, lptr) __builtin_amdgcn_global_load_lds( \
  (const __attribute__((address_space(1))) void*)(gptr), \
  (__attribute__((address_space(3))) void*)(lptr), 16, 0, 0)

// fp32 -> bf16 (RNE), vectorized float4 -> ushort4
__global__ __launch_bounds__(256) void cvt_kernel(const float* __restrict__ in,
                                                  unsigned short* __restrict__ out, int n4)
{
  int i = blockIdx.x * blockDim.x + threadIdx.x;
  int stride = gridDim.x * blockDim.x;
  for (; i < n4; i += stride) {
    float4 v = reinterpret_cast<const float4*>(in)[i];
    ushort4 o;
    o.x = f2bf(v.x); o.y = f2bf(v.y); o.z = f2bf(v.z); o.w = f2bf(v.w);
    reinterpret_cast<ushort4*>(out)[i] = o;
  }
}

// Fused bf16 MFMA projection GEMM. 128x128 tile, BK=32, 4 waves (2x2).
// MODE 0 (K): krow[bm,head,t] direct store; ksum partials -> ksum4[p][bm][d]
//             (p = (t-tile&1)*2 + wm), NO atomics, NO pre-zero needed.
// MODE 1 (Q): zden[bm,head,t] = sum_d q[t,d]*(sum_p ksum4[p][bm][d]) direct store.
template<int MODE>
__global__ __launch_bounds__(256) void gemm_proj(
    const bf16* __restrict__ A, const bf16* __restrict__ Bw,
    const float* __restrict__ bias,
    float* __restrict__ krow, float* __restrict__ ksum4,
    const float* __restrict__ ksum4_in, float* __restrict__ zden)
{
  __shared__ bf16 As[128 * 32];
  __shared__ bf16 Bs[128 * 32];

  const int tid  = threadIdx.x;
  const int lane = tid & 63;
  const int wid  = tid >> 6;
  const int wm   = wid >> 1, wn = wid & 1;
  const int tm   = blockIdx.x, tn = blockIdx.y;

  f32x4 acc[4][4];
#pragma unroll
  for (int i = 0; i < 4; i++)
#pragma unroll
    for (int j = 0; j < 4; j++) acc[i][j] = (f32x4){0.f, 0.f, 0.f, 0.f};

  const bf16* Ab = A  + (size_t)(tm * 128) * C_;
  const bf16* Bb = Bw + (size_t)(tn * 128) * C_;

  const int strow = tid >> 2;
  const int skoff = (tid & 3) * 8;
  const int fr = lane & 15;
  const int fq = lane >> 4;
  const int fk = fq * 8;

  for (int kc = 0; kc < C_; kc += 32) {
    GLOAD16(Ab + (size_t)strow * C_ + kc + skoff,        As + strow * 32 + skoff);
    GLOAD16(Ab + (size_t)(strow + 64) * C_ + kc + skoff, As + (strow + 64) * 32 + skoff);
    GLOAD16(Bb + (size_t)strow * C_ + kc + skoff,        Bs + strow * 32 + skoff);
    GLOAD16(Bb + (size_t)(strow + 64) * C_ + kc + skoff, Bs + (strow + 64) * 32 + skoff);
    asm volatile("s_waitcnt vmcnt(0)" ::: "memory");
    __syncthreads();

    bf16x8 af[4], bfr[4];
#pragma unroll
    for (int i = 0; i < 4; i++)
      af[i] = *reinterpret_cast<const bf16x8*>(&As[(wm * 64 + i * 16 + fr) * 32 + fk]);
#pragma unroll
    for (int j = 0; j < 4; j++)
      bfr[j] = *reinterpret_cast<const bf16x8*>(&Bs[(wn * 64 + j * 16 + fr) * 32 + fk]);
#pragma unroll
    for (int i = 0; i < 4; i++)
#pragma unroll
      for (int j = 0; j < 4; j++)
        acc[i][j] = __builtin_amdgcn_mfma_f32_16x16x32_bf16(af[i], bfr[j], acc[i][j], 0, 0, 0);
    __syncthreads();
  }

  const int bm   = tm >> 1;
  const int head = tn * 2 + wn;
  float bj[4];
#pragma unroll
  for (int j = 0; j < 4; j++) bj[j] = bias[tn * 128 + wn * 64 + j * 16 + fr];

  if (MODE == 0) {
    float cs[4] = {0.f, 0.f, 0.f, 0.f};
#pragma unroll
    for (int i = 0; i < 4; i++) {
#pragma unroll
      for (int r = 0; r < 4; r++) {
        float rs = 0.f;
#pragma unroll
        for (int j = 0; j < 4; j++) {
          float v = elu1(acc[i][j][r] + bj[j]);
          rs += v;
          cs[j] += v;
        }
#pragma unroll
        for (int m = 1; m < 16; m <<= 1) rs += __shfl_xor(rs, m);
        if (fr == 0) {
          int grow = tm * 128 + wm * 64 + i * 16 + fq * 4 + r;
          krow[((size_t)bm * NH + head) * T_ + (grow & 255)] = rs;
        }
      }
    }
    // column-sum partial: reduce over fq groups, write disjoint slot (no atomics)
    const int part = (tm & 1) * 2 + wm;
#pragma unroll
    for (int j = 0; j < 4; j++) {
      cs[j] += __shfl_xor(cs[j], 16);
      cs[j] += __shfl_xor(cs[j], 32);
      if (fq == 0)
        ksum4[((size_t)part * BM_ + bm) * C_ + tn * 128 + wn * 64 + j * 16 + fr] = cs[j];
    }
  } else {
    float ks[4];
#pragma unroll
    for (int j = 0; j < 4; j++) {
      size_t col = (size_t)bm * C_ + tn * 128 + wn * 64 + j * 16 + fr;
      ks[j] = ksum4_in[col] + ksum4_in[(size_t)BM_ * C_ + col]
            + ksum4_in[2 * (size_t)BM_ * C_ + col] + ksum4_in[3 * (size_t)BM_ * C_ + col];
    }
#pragma unroll
    for (int i = 0; i < 4; i++) {
#pragma unroll
      for (int r = 0; r < 4; r++) {
        float zs = 0.f;
#pragma unroll
        for (int j = 0; j < 4; j++) zs = fmaf(elu1(acc[i][j][r] + bj[j]), ks[j], zs);
#pragma unroll
        for (int m = 1; m < 16; m <<= 1) zs += __shfl_xor(zs, m);
        if (fr == 0) {
          int grow = tm * 128 + wm * 64 + i * 16 + fq * 4 + r;
          zden[((size_t)bm * NH + head) * T_ + (grow & 255)] = zs;
        }
      }
    }
  }
}

// xk_n[c] = sum_t krow_n[t] * x[bm,t,c]; srow_n = sum_t krow_n[t]. bf16 x, fp32 accum.
__global__ __launch_bounds__(256) void xk_kernel(
    const unsigned short* __restrict__ xb, const float* __restrict__ krow,
    float* __restrict__ xk, float* __restrict__ srow)
{
  const int bm = blockIdx.x, tid = threadIdx.x;
  __shared__ float krs[NH * T_];
#pragma unroll
  for (int p = 0; p < 8; p++) krs[tid + p * 256] = krow[(size_t)bm * NH * T_ + tid + p * 256];
  __syncthreads();
  float a0[8], a1[8];
#pragma unroll
  for (int n = 0; n < 8; n++) { a0[n] = 0.f; a1[n] = 0.f; }
  const unsigned short* xp = xb + (size_t)bm * T_ * C_ + tid * 2;
  for (int t = 0; t < T_; t++) {
    ushort2 u = *reinterpret_cast<const ushort2*>(xp + (size_t)t * C_);
    float x0 = bf2f(u.x), x1 = bf2f(u.y);
#pragma unroll
    for (int n = 0; n < 8; n++) {
      float kr = krs[n * T_ + t];
      a0[n] = fmaf(kr, x0, a0[n]);
      a1[n] = fmaf(kr, x1, a1[n]);
    }
  }
#pragma unroll
  for (int n = 0; n < 8; n++)
    *reinterpret_cast<float2*>(&xk[((size_t)bm * NH + n) * C_ + tid * 2]) = make_float2(a0[n], a1[n]);
  if (tid < 8) {
    float s = 0.f;
    for (int t = 0; t < T_; t++) s += krs[tid * T_ + t];
    srow[bm * NH + tid] = s;
  }
}

// colsum[bm,h,e] = Wv[h*64+e,:] . xk[bm,h,:] + srow[bm,h]*bv[h*64+e]
__global__ __launch_bounds__(256) void colsum_kernel(
    const float* __restrict__ xk, const float* __restrict__ srow,
    const float* __restrict__ Wv, const float* __restrict__ bv,
    float* __restrict__ cs_g)
{
  const int bm0 = blockIdx.x * 8, h = blockIdx.y, tid = threadIdx.x;
  __shared__ float4 xs4[8][128];
#pragma unroll
  for (int p = 0; p < 4; p++) {
    int idx = tid + p * 256;
    int bmr = idx >> 7, c4 = idx & 127;
    xs4[bmr][c4] = *reinterpret_cast<const float4*>(
        xk + ((size_t)(bm0 + bmr) * NH + h) * C_ + c4 * 4);
  }
  __syncthreads();
  const int e = tid & 63, bs = tid >> 6;
  const float4* wv4 = reinterpret_cast<const float4*>(Wv + (size_t)(h * DH + e) * C_);
  float acc0 = 0.f, acc1 = 0.f;
#pragma unroll 4
  for (int c4 = 0; c4 < 128; c4++) {
    float4 w = wv4[c4];
    float4 a = xs4[bs * 2][c4];
    float4 b = xs4[bs * 2 + 1][c4];
    acc0 += w.x * a.x + w.y * a.y + w.z * a.z + w.w * a.w;
    acc1 += w.x * b.x + w.y * b.y + w.z * b.z + w.w * b.w;
  }
  float bve = bv[h * DH + e];
  int bmA = bm0 + bs * 2, bmB = bmA + 1;
  cs_g[((size_t)bmA * NH + h) * DH + e] = acc0 + srow[bmA * NH + h] * bve;
  cs_g[((size_t)bmB * NH + h) * DH + e] = acc1 + srow[bmB * NH + h] * bve;
}

// wbuf[bm,h,cp] = sum_e cs[bm,h,e] * Wp[cp, h*64+e]
__global__ __launch_bounds__(256) void wbuf_kernel(
    const float* __restrict__ cs_g, const float* __restrict__ Wp,
    float* __restrict__ wbuf)
{
  const int cpt = blockIdx.x, h = blockIdx.y, bm0 = blockIdx.z * 16;
  const int tid = threadIdx.x;
  __shared__ float4 csL4[16][16];
  {
    int bmr = tid >> 4, e4 = tid & 15;
    csL4[bmr][e4] = *reinterpret_cast<const float4*>(
        cs_g + ((size_t)(bm0 + bmr) * NH + h) * DH + e4 * 4);
  }
  __syncthreads();
  const int cp = cpt * 256 + tid;
  float4 wp[16];
  const float4* wpr = reinterpret_cast<const float4*>(Wp + (size_t)cp * C_ + h * DH);
#pragma unroll
  for (int e4 = 0; e4 < 16; e4++) wp[e4] = wpr[e4];
#pragma unroll
  for (int bmr = 0; bmr < 16; bmr++) {
    float acc = 0.f;
#pragma unroll
    for (int e4 = 0; e4 < 16; e4++) {
      float4 c = csL4[bmr][e4];
      acc += wp[e4].x * c.x + wp[e4].y * c.y + wp[e4].z * c.z + wp[e4].w * c.w;
    }
    wbuf[((size_t)(bm0 + bmr) * NH + h) * C_ + cp] = acc;
  }
}

// out[bm,t,c'] = sum_n z_n[t]*w_n[c'] + bp[c'],  z = 1/(zden+eps)
__global__ __launch_bounds__(256) void out_kernel(
    const float* __restrict__ zden, const float* __restrict__ wbuf,
    const float* __restrict__ bp, float* __restrict__ out)
{
  const int bm = blockIdx.x, tt = blockIdx.y, tid = threadIdx.x;
  __shared__ float zs[NH][64];
#pragma unroll
  for (int p = 0; p < 2; p++) {
    int idx = tid + p * 256;
    int n = idx >> 6, t = idx & 63;
    zs[n][t] = 1.f / (zden[((size_t)bm * NH + n) * T_ + tt * 64 + t] + 1e-6f);
  }
  float2 wv[8];
  const int c2 = tid * 2;
#pragma unroll
  for (int n = 0; n < 8; n++)
    wv[n] = *reinterpret_cast<const float2*>(wbuf + ((size_t)bm * NH + n) * C_ + c2);
  float2 bpv = *reinterpret_cast<const float2*>(bp + c2);
  __syncthreads();
  float* ob = out + ((size_t)bm * T_ + tt * 64) * C_;
  for (int t = 0; t < 64; t++) {
    float o0 = bpv.x, o1 = bpv.y;
#pragma unroll
    for (int n = 0; n < 8; n++) { float z = zs[n][t]; o0 = fmaf(z, wv[n].x, o0); o1 = fmaf(z, wv[n].y, o1); }
    *reinterpret_cast<float2*>(ob + (size_t)t * C_ + c2) = make_float2(o0, o1);
  }
}

extern "C" void kernel_launch(void* const* d_in, const int* in_sizes, int n_in,
                              void* d_out, int out_size, void* d_ws, size_t ws_size,
                              hipStream_t stream)
{
  const float* x  = (const float*)d_in[0];
  const float* Wq = (const float*)d_in[1];
  const float* bq = (const float*)d_in[2];
  const float* Wk = (const float*)d_in[3];
  const float* bk = (const float*)d_in[4];
  const float* Wv = (const float*)d_in[5];
  const float* bv = (const float*)d_in[6];
  const float* Wp = (const float*)d_in[7];
  const float* bp = (const float*)d_in[8];
  float* out = (float*)d_out;

  float* ws    = (float*)d_ws;
  float* zden  = ws;                        // 262144 f
  float* ksum4 = zden + 262144;             // 4*128*512 = 262144 f
  float* krow  = ksum4 + 262144;            // 262144 f
  float* srow  = krow + 262144;             // 1024 f
  float* xk    = srow + 1024;               // 524288 f
  float* cs    = xk + 524288;               // 65536 f
  float* wbuf  = cs + 65536;                // 524288 f
  unsigned short* xb  = (unsigned short*)(wbuf + 524288);  // 16.7M bf16
  unsigned short* wkb = xb + 16777216;
  unsigned short* wqb = wkb + 262144;

  cvt_kernel<<<2048, 256, 0, stream>>>(x,  xb,  16777216 / 4);
  cvt_kernel<<<256,  256, 0, stream>>>(Wk, wkb, 262144 / 4);
  cvt_kernel<<<256,  256, 0, stream>>>(Wq, wqb, 262144 / 4);

  dim3 g(256, 4);
  gemm_proj<0><<<g, 256, 0, stream>>>((const bf16*)xb, (const bf16*)wkb, bk,
                                      krow, ksum4, nullptr, nullptr);
  xk_kernel<<<BM_, 256, 0, stream>>>(xb, krow, xk, srow);
  colsum_kernel<<<dim3(16, 8), 256, 0, stream>>>(xk, srow, Wv, bv, cs);
  wbuf_kernel<<<dim3(2, 8, 8), 256, 0, stream>>>(cs, Wp, wbuf);
  gemm_proj<1><<<g, 256, 0, stream>>>((const bf16*)xb, (const bf16*)wqb, bq,
                                      nullptr, nullptr, ksum4, zden);
  out_kernel<<<dim3(BM_, 4), 256, 0, stream>>>(zden, wbuf, bp, out);
}

// Round 5
// 135.562 us; speedup vs baseline: 10.3095x; 1.1510x over previous
//
#include <hip/hip_runtime.h>
#include <hip/hip_bf16.h>

#define BM_ 128   // B*M
#define T_  256
#define C_  512
#define NH  8
#define DH  64

typedef __bf16 bf16;
typedef __attribute__((ext_vector_type(8))) __bf16 bf16x8;
typedef __attribute__((ext_vector_type(4))) float f32x4;

__device__ __forceinline__ float elu1(float v){ return v > 0.f ? v + 1.f : __expf(v); }

__device__ __forceinline__ unsigned short f2bf(float f){
  unsigned u = __float_as_uint(f);
  u += 0x7fffu + ((u >> 16) & 1u);
  return (unsigned short)(u >> 16);
}

__device__ __forceinline__ float bf2f(unsigned short b){
  return __uint_as_float(((unsigned)b) << 16);
}

#define GLOAD16(gptr, lptr) __builtin_amdgcn_global_load_lds( \
  (const __attribute__((address_space(1))) void*)(gptr), \
  (__attribute__((address_space(3))) void*)(lptr), 16, 0, 0)

// fused fp32->bf16 (RNE) for x, Wk, Wq in one launch
__global__ __launch_bounds__(256) void cvt3_kernel(
    const float* __restrict__ a, int na4,
    const float* __restrict__ b, int nb4,
    const float* __restrict__ c, int nc4,
    unsigned short* __restrict__ oa, unsigned short* __restrict__ ob,
    unsigned short* __restrict__ oc)
{
  int i = blockIdx.x * blockDim.x + threadIdx.x;
  int stride = gridDim.x * blockDim.x;
  int total = na4 + nb4 + nc4;
  for (; i < total; i += stride) {
    const float* src; unsigned short* dst; int idx;
    if (i < na4)            { src = a; dst = oa; idx = i; }
    else if (i < na4 + nb4) { src = b; dst = ob; idx = i - na4; }
    else                    { src = c; dst = oc; idx = i - na4 - nb4; }
    float4 v = reinterpret_cast<const float4*>(src)[idx];
    ushort4 o;
    o.x = f2bf(v.x); o.y = f2bf(v.y); o.z = f2bf(v.z); o.w = f2bf(v.w);
    reinterpret_cast<ushort4*>(dst)[idx] = o;
  }
}

// Fused bf16 MFMA projection GEMM. 128x128 tile, BK=32, 2-phase LDS double-buffer,
// XCD-bijective block swizzle (A-tile's 4 tn-blocks land consecutively on one XCD).
// MODE 0 (K): krow direct store; ksum partials -> ksum4[p][bm][d], no atomics.
// MODE 1 (Q): zden[bm,head,t] = sum_d q[t,d]*(sum_p ksum4[p][bm][d]) direct store.
template<int MODE>
__global__ __launch_bounds__(256) void gemm_proj(
    const bf16* __restrict__ A, const bf16* __restrict__ Bw,
    const float* __restrict__ bias,
    float* __restrict__ krow, float* __restrict__ ksum4,
    const float* __restrict__ ksum4_in, float* __restrict__ zden)
{
  __shared__ bf16 As[2][128 * 32];
  __shared__ bf16 Bs[2][128 * 32];

  const int tid  = threadIdx.x;
  const int lane = tid & 63;
  const int wid  = tid >> 6;
  const int wm   = wid >> 1, wn = wid & 1;

  // XCD swizzle: 1024 blocks, 8 XCDs, 128 per XCD; tn fastest within logical id.
  const int L  = (blockIdx.x & 7) * 128 + (blockIdx.x >> 3);
  const int tn = L & 3, tm = L >> 2;

  f32x4 acc[4][4];
#pragma unroll
  for (int i = 0; i < 4; i++)
#pragma unroll
    for (int j = 0; j < 4; j++) acc[i][j] = (f32x4){0.f, 0.f, 0.f, 0.f};

  const bf16* Ab = A  + (size_t)(tm * 128) * C_;
  const bf16* Bb = Bw + (size_t)(tn * 128) * C_;

  const int r0 = tid >> 2, r1 = r0 + 64;
  const int sl = (tid & 3) * 8;          // 16B slot within 64B row
  const int fr = lane & 15;
  const int fq = lane >> 4;
  const int fk = fq * 8;

#define STAGE(buf, kc) do { \
    GLOAD16(Ab + (size_t)r0 * C_ + (kc) + sl, As[buf] + r0 * 32 + sl); \
    GLOAD16(Ab + (size_t)r1 * C_ + (kc) + sl, As[buf] + r1 * 32 + sl); \
    GLOAD16(Bb + (size_t)r0 * C_ + (kc) + sl, Bs[buf] + r0 * 32 + sl); \
    GLOAD16(Bb + (size_t)r1 * C_ + (kc) + sl, Bs[buf] + r1 * 32 + sl); \
  } while (0)

  STAGE(0, 0);
  asm volatile("s_waitcnt vmcnt(0)" ::: "memory");
  __syncthreads();

  for (int it = 0; it < 15; ++it) {
    const int cur = it & 1;
    STAGE(cur ^ 1, (it + 1) * 32);       // prefetch next tile into other buffer
    bf16x8 af[4], bfr[4];
#pragma unroll
    for (int i = 0; i < 4; i++)
      af[i] = *reinterpret_cast<const bf16x8*>(&As[cur][(wm * 64 + i * 16 + fr) * 32 + fk]);
#pragma unroll
    for (int j = 0; j < 4; j++)
      bfr[j] = *reinterpret_cast<const bf16x8*>(&Bs[cur][(wn * 64 + j * 16 + fr) * 32 + fk]);
#pragma unroll
    for (int i = 0; i < 4; i++)
#pragma unroll
      for (int j = 0; j < 4; j++)
        acc[i][j] = __builtin_amdgcn_mfma_f32_16x16x32_bf16(af[i], bfr[j], acc[i][j], 0, 0, 0);
    asm volatile("s_waitcnt vmcnt(0)" ::: "memory");
    __syncthreads();
  }
  {  // final K-step, no prefetch
    bf16x8 af[4], bfr[4];
#pragma unroll
    for (int i = 0; i < 4; i++)
      af[i] = *reinterpret_cast<const bf16x8*>(&As[1][(wm * 64 + i * 16 + fr) * 32 + fk]);
#pragma unroll
    for (int j = 0; j < 4; j++)
      bfr[j] = *reinterpret_cast<const bf16x8*>(&Bs[1][(wn * 64 + j * 16 + fr) * 32 + fk]);
#pragma unroll
    for (int i = 0; i < 4; i++)
#pragma unroll
      for (int j = 0; j < 4; j++)
        acc[i][j] = __builtin_amdgcn_mfma_f32_16x16x32_bf16(af[i], bfr[j], acc[i][j], 0, 0, 0);
  }
#undef STAGE

  const int bm   = tm >> 1;
  const int head = tn * 2 + wn;
  float bj[4];
#pragma unroll
  for (int j = 0; j < 4; j++) bj[j] = bias[tn * 128 + wn * 64 + j * 16 + fr];

  if (MODE == 0) {
    float cs[4] = {0.f, 0.f, 0.f, 0.f};
#pragma unroll
    for (int i = 0; i < 4; i++) {
#pragma unroll
      for (int r = 0; r < 4; r++) {
        float rs = 0.f;
#pragma unroll
        for (int j = 0; j < 4; j++) {
          float v = elu1(acc[i][j][r] + bj[j]);
          rs += v;
          cs[j] += v;
        }
#pragma unroll
        for (int m = 1; m < 16; m <<= 1) rs += __shfl_xor(rs, m);
        if (fr == 0) {
          int grow = tm * 128 + wm * 64 + i * 16 + fq * 4 + r;
          krow[((size_t)bm * NH + head) * T_ + (grow & 255)] = rs;
        }
      }
    }
    const int part = (tm & 1) * 2 + wm;
#pragma unroll
    for (int j = 0; j < 4; j++) {
      cs[j] += __shfl_xor(cs[j], 16);
      cs[j] += __shfl_xor(cs[j], 32);
      if (fq == 0)
        ksum4[((size_t)part * BM_ + bm) * C_ + tn * 128 + wn * 64 + j * 16 + fr] = cs[j];
    }
  } else {
    float ks[4];
#pragma unroll
    for (int j = 0; j < 4; j++) {
      size_t col = (size_t)bm * C_ + tn * 128 + wn * 64 + j * 16 + fr;
      ks[j] = ksum4_in[col] + ksum4_in[(size_t)BM_ * C_ + col]
            + ksum4_in[2 * (size_t)BM_ * C_ + col] + ksum4_in[3 * (size_t)BM_ * C_ + col];
    }
#pragma unroll
    for (int i = 0; i < 4; i++) {
#pragma unroll
      for (int r = 0; r < 4; r++) {
        float zs = 0.f;
#pragma unroll
        for (int j = 0; j < 4; j++) zs = fmaf(elu1(acc[i][j][r] + bj[j]), ks[j], zs);
#pragma unroll
        for (int m = 1; m < 16; m <<= 1) zs += __shfl_xor(zs, m);
        if (fr == 0) {
          int grow = tm * 128 + wm * 64 + i * 16 + fq * 4 + r;
          zden[((size_t)bm * NH + head) * T_ + (grow & 255)] = zs;
        }
      }
    }
  }
}

// xk2[th][bm,n,c] = sum_{t in half th} krow_n[t] * x[bm,t,c]; srow2 likewise.
__global__ __launch_bounds__(256) void xk_kernel(
    const unsigned short* __restrict__ xb, const float* __restrict__ krow,
    float* __restrict__ xk2, float* __restrict__ srow2)
{
  const int bm = blockIdx.x, th = blockIdx.y, tid = threadIdx.x;
  __shared__ float krs[NH * 128];
#pragma unroll
  for (int p = 0; p < 4; p++) {
    int idx = tid + p * 256;
    int n = idx >> 7, t = idx & 127;
    krs[idx] = krow[((size_t)bm * NH + n) * T_ + th * 128 + t];
  }
  __syncthreads();
  float a0[8], a1[8];
#pragma unroll
  for (int n = 0; n < 8; n++) { a0[n] = 0.f; a1[n] = 0.f; }
  const unsigned short* xp = xb + ((size_t)bm * T_ + th * 128) * C_ + tid * 2;
  for (int t = 0; t < 128; t++) {
    ushort2 u = *reinterpret_cast<const ushort2*>(xp + (size_t)t * C_);
    float x0 = bf2f(u.x), x1 = bf2f(u.y);
#pragma unroll
    for (int n = 0; n < 8; n++) {
      float kr = krs[n * 128 + t];
      a0[n] = fmaf(kr, x0, a0[n]);
      a1[n] = fmaf(kr, x1, a1[n]);
    }
  }
#pragma unroll
  for (int n = 0; n < 8; n++)
    *reinterpret_cast<float2*>(&xk2[(((size_t)th * BM_ + bm) * NH + n) * C_ + tid * 2])
        = make_float2(a0[n], a1[n]);
  if (tid < 8) {
    float s = 0.f;
    for (int t = 0; t < 128; t++) s += krs[tid * 128 + t];
    srow2[((size_t)th * BM_ + bm) * NH + tid] = s;
  }
}

// colsum[bm,h,e] = Wv[h*64+e,:] . xk[bm,h,:] + srow[bm,h]*bv[h*64+e]
__global__ __launch_bounds__(256) void colsum_kernel(
    const float* __restrict__ xk2, const float* __restrict__ srow2,
    const float* __restrict__ Wv, const float* __restrict__ bv,
    float* __restrict__ cs_g)
{
  const int bm0 = blockIdx.x * 8, h = blockIdx.y, tid = threadIdx.x;
  __shared__ float4 xs4[8][128];
#pragma unroll
  for (int p = 0; p < 4; p++) {
    int idx = tid + p * 256;
    int bmr = idx >> 7, c4 = idx & 127;
    float4 u = *reinterpret_cast<const float4*>(
        xk2 + (((size_t)0 * BM_ + bm0 + bmr) * NH + h) * C_ + c4 * 4);
    float4 w = *reinterpret_cast<const float4*>(
        xk2 + (((size_t)1 * BM_ + bm0 + bmr) * NH + h) * C_ + c4 * 4);
    xs4[bmr][c4] = make_float4(u.x + w.x, u.y + w.y, u.z + w.z, u.w + w.w);
  }
  __syncthreads();
  const int e = tid & 63, bs = tid >> 6;
  const float4* wv4 = reinterpret_cast<const float4*>(Wv + (size_t)(h * DH + e) * C_);
  float acc0 = 0.f, acc1 = 0.f;
#pragma unroll 4
  for (int c4 = 0; c4 < 128; c4++) {
    float4 w = wv4[c4];
    float4 a = xs4[bs * 2][c4];
    float4 b = xs4[bs * 2 + 1][c4];
    acc0 += w.x * a.x + w.y * a.y + w.z * a.z + w.w * a.w;
    acc1 += w.x * b.x + w.y * b.y + w.z * b.z + w.w * b.w;
  }
  float bve = bv[h * DH + e];
  int bmA = bm0 + bs * 2, bmB = bmA + 1;
  float sA = srow2[(size_t)bmA * NH + h] + srow2[(size_t)(BM_ + bmA) * NH + h];
  float sB = srow2[(size_t)bmB * NH + h] + srow2[(size_t)(BM_ + bmB) * NH + h];
  cs_g[((size_t)bmA * NH + h) * DH + e] = acc0 + sA * bve;
  cs_g[((size_t)bmB * NH + h) * DH + e] = acc1 + sB * bve;
}

// wbuf[bm,h,cp] = sum_e cs[bm,h,e] * Wp[cp, h*64+e]
__global__ __launch_bounds__(256) void wbuf_kernel(
    const float* __restrict__ cs_g, const float* __restrict__ Wp,
    float* __restrict__ wbuf)
{
  const int cpt = blockIdx.x, h = blockIdx.y, bm0 = blockIdx.z * 16;
  const int tid = threadIdx.x;
  __shared__ float4 csL4[16][16];
  {
    int bmr = tid >> 4, e4 = tid & 15;
    csL4[bmr][e4] = *reinterpret_cast<const float4*>(
        cs_g + ((size_t)(bm0 + bmr) * NH + h) * DH + e4 * 4);
  }
  __syncthreads();
  const int cp = cpt * 256 + tid;
  float4 wp[16];
  const float4* wpr = reinterpret_cast<const float4*>(Wp + (size_t)cp * C_ + h * DH);
#pragma unroll
  for (int e4 = 0; e4 < 16; e4++) wp[e4] = wpr[e4];
#pragma unroll
  for (int bmr = 0; bmr < 16; bmr++) {
    float acc = 0.f;
#pragma unroll
    for (int e4 = 0; e4 < 16; e4++) {
      float4 c = csL4[bmr][e4];
      acc += wp[e4].x * c.x + wp[e4].y * c.y + wp[e4].z * c.z + wp[e4].w * c.w;
    }
    wbuf[((size_t)(bm0 + bmr) * NH + h) * C_ + cp] = acc;
  }
}

// out[bm,t,c'] = sum_n z_n[t]*w_n[c'] + bp[c'],  z = 1/(zden+eps)
__global__ __launch_bounds__(256) void out_kernel(
    const float* __restrict__ zden, const float* __restrict__ wbuf,
    const float* __restrict__ bp, float* __restrict__ out)
{
  const int bm = blockIdx.x, tt = blockIdx.y, tid = threadIdx.x;
  __shared__ float zs[NH][64];
#pragma unroll
  for (int p = 0; p < 2; p++) {
    int idx = tid + p * 256;
    int n = idx >> 6, t = idx & 63;
    zs[n][t] = 1.f / (zden[((size_t)bm * NH + n) * T_ + tt * 64 + t] + 1e-6f);
  }
  float2 wv[8];
  const int c2 = tid * 2;
#pragma unroll
  for (int n = 0; n < 8; n++)
    wv[n] = *reinterpret_cast<const float2*>(wbuf + ((size_t)bm * NH + n) * C_ + c2);
  float2 bpv = *reinterpret_cast<const float2*>(bp + c2);
  __syncthreads();
  float* ob = out + ((size_t)bm * T_ + tt * 64) * C_;
  for (int t = 0; t < 64; t++) {
    float o0 = bpv.x, o1 = bpv.y;
#pragma unroll
    for (int n = 0; n < 8; n++) { float z = zs[n][t]; o0 = fmaf(z, wv[n].x, o0); o1 = fmaf(z, wv[n].y, o1); }
    *reinterpret_cast<float2*>(ob + (size_t)t * C_ + c2) = make_float2(o0, o1);
  }
}

extern "C" void kernel_launch(void* const* d_in, const int* in_sizes, int n_in,
                              void* d_out, int out_size, void* d_ws, size_t ws_size,
                              hipStream_t stream)
{
  const float* x  = (const float*)d_in[0];
  const float* Wq = (const float*)d_in[1];
  const float* bq = (const float*)d_in[2];
  const float* Wk = (const float*)d_in[3];
  const float* bk = (const float*)d_in[4];
  const float* Wv = (const float*)d_in[5];
  const float* bv = (const float*)d_in[6];
  const float* Wp = (const float*)d_in[7];
  const float* bp = (const float*)d_in[8];
  float* out = (float*)d_out;

  float* ws    = (float*)d_ws;
  float* zden  = ws;                        // 262144 f
  float* ksum4 = zden + 262144;             // 262144 f
  float* krow  = ksum4 + 262144;            // 262144 f
  float* srow2 = krow + 262144;             // 2048 f
  float* xk2   = srow2 + 2048;              // 1048576 f
  float* cs    = xk2 + 1048576;             // 65536 f
  float* wbuf  = cs + 65536;                // 524288 f
  unsigned short* xb  = (unsigned short*)(wbuf + 524288);  // 16.7M bf16
  unsigned short* wkb = xb + 16777216;
  unsigned short* wqb = wkb + 262144;

  cvt3_kernel<<<2048, 256, 0, stream>>>(x, 16777216 / 4, Wk, 262144 / 4, Wq, 262144 / 4,
                                        xb, wkb, wqb);

  gemm_proj<0><<<1024, 256, 0, stream>>>((const bf16*)xb, (const bf16*)wkb, bk,
                                         krow, ksum4, nullptr, nullptr);
  xk_kernel<<<dim3(BM_, 2), 256, 0, stream>>>(xb, krow, xk2, srow2);
  colsum_kernel<<<dim3(16, 8), 256, 0, stream>>>(xk2, srow2, Wv, bv, cs);
  wbuf_kernel<<<dim3(2, 8, 8), 256, 0, stream>>>(cs, Wp, wbuf);
  gemm_proj<1><<<1024, 256, 0, stream>>>((const bf16*)xb, (const bf16*)wqb, bq,
                                         nullptr, nullptr, ksum4, zden);
  out_kernel<<<dim3(BM_, 4), 256, 0, stream>>>(zden, wbuf, bp, out);
}

// Round 6
// 115.907 us; speedup vs baseline: 12.0578x; 1.1696x over previous
//
#include <hip/hip_runtime.h>
#include <hip/hip_bf16.h>

#define BM_ 128   // B*M
#define T_  256
#define C_  512
#define NH  8
#define DH  64

typedef __bf16 bf16;
typedef __attribute__((ext_vector_type(8))) __bf16 bf16x8;
typedef __attribute__((ext_vector_type(4))) float f32x4;

__device__ __forceinline__ float elu1(float v){ return v > 0.f ? v + 1.f : __expf(v); }

__device__ __forceinline__ unsigned short f2bf(float f){
  unsigned u = __float_as_uint(f);
  u += 0x7fffu + ((u >> 16) & 1u);
  return (unsigned short)(u >> 16);
}

__device__ __forceinline__ float bf2f(unsigned short b){
  return __uint_as_float(((unsigned)b) << 16);
}

#define GLOAD16(gptr, lptr) __builtin_amdgcn_global_load_lds( \
  (const __attribute__((address_space(1))) void*)(gptr), \
  (__attribute__((address_space(3))) void*)(lptr), 16, 0, 0)

#define FENCE() asm volatile("" ::: "memory")

// fused fp32->bf16 (RNE) for x, Wk, Wq in one launch
__global__ __launch_bounds__(256) void cvt3_kernel(
    const float* __restrict__ a, int na4,
    const float* __restrict__ b, int nb4,
    const float* __restrict__ c, int nc4,
    unsigned short* __restrict__ oa, unsigned short* __restrict__ ob,
    unsigned short* __restrict__ oc)
{
  int i = blockIdx.x * blockDim.x + threadIdx.x;
  int stride = gridDim.x * blockDim.x;
  int total = na4 + nb4 + nc4;
  for (; i < total; i += stride) {
    const float* src; unsigned short* dst; int idx;
    if (i < na4)            { src = a; dst = oa; idx = i; }
    else if (i < na4 + nb4) { src = b; dst = ob; idx = i - na4; }
    else                    { src = c; dst = oc; idx = i - na4 - nb4; }
    float4 v = reinterpret_cast<const float4*>(src)[idx];
    ushort4 o;
    o.x = f2bf(v.x); o.y = f2bf(v.y); o.z = f2bf(v.z); o.w = f2bf(v.w);
    reinterpret_cast<ushort4*>(dst)[idx] = o;
  }
}

// Fused bf16 MFMA projection GEMM, 256x256 tile, BK=64, 8 waves (2M x 4N),
// per-wave 128x64 output. LDS 128KB double-buffered, XOR-swizzled (slot ^= row&7)
// via pre-swizzled global source (linear global_load_lds dest). 4 phases per
// K-tile of 16 MFMA each with s_setprio; stages front-loaded (4/2/2/0 loads)
// so the once-per-tile vmcnt(0) drain overlaps ~3 phases of compute.
// Raw s_barrier (+compiler fences) -- no __syncthreads (would force drain).
// MODE 0 (K): krow[bm,head,t] direct; ksum partials -> ksum2[wr][bm][d].
// MODE 1 (Q): zden[bm,head,t] = sum_d q[t,d]*(ksum2[0]+ksum2[1]) direct.
template<int MODE>
__global__ __launch_bounds__(512, 2) void gemm_proj(
    const bf16* __restrict__ A, const bf16* __restrict__ Bw,
    const float* __restrict__ bias,
    float* __restrict__ krow, float* __restrict__ ksum2,
    const float* __restrict__ ksum2_in, float* __restrict__ zden)
{
  __shared__ bf16 As[2][256 * 64];
  __shared__ bf16 Bs[2][256 * 64];

  const int tid  = threadIdx.x;
  const int lane = tid & 63;
  const int wid  = tid >> 6;
  const int wr   = wid >> 2, wc = wid & 3;    // 2M x 4N wave grid

  // XCD-bijective swizzle: 256 blocks, 32 per XCD; tn fastest (A-tile L2 reuse).
  const int L  = ((blockIdx.x & 7) << 5) + (blockIdx.x >> 3);
  const int tn = L & 1, tm = L >> 1;          // tm == bm (M-tile 256 == T_)

  const bf16* Ab = A  + (size_t)(tm * 256) * C_;
  const bf16* Bb = Bw + (size_t)(tn * 256) * C_;

  const int srow  = tid >> 3;   // staging: 64 rows per call, 8 x 16B slots/row
  const int sslot = tid & 7;
  const int fr = lane & 15, fq = lane >> 4;

  f32x4 acc[8][4];
#pragma unroll
  for (int m = 0; m < 8; ++m)
#pragma unroll
    for (int n = 0; n < 4; ++n) acc[m][n] = (f32x4){0.f, 0.f, 0.f, 0.f};

  // stage half h (128 rows) of tile kt into buffer b; LDS dest linear,
  // global source pre-swizzled so LDS slot s holds k-slot s^(row&7).
#define STG(XS, Xb, b, h, kt) do { \
  _Pragma("unroll") \
  for (int q = 0; q < 2; ++q) { \
    int r_ = (h) * 128 + q * 64 + srow; \
    GLOAD16(Xb + (size_t)r_ * C_ + (kt) * 64 + ((sslot ^ (r_ & 7)) << 3), \
            &XS[b][(((h) * 128 + q * 64) << 6) + (tid << 3)]); \
  } } while (0)

  // LDS elem offset for (row, 16B-slot) with read-side swizzle
#define LOFF(row, sl) (((row) << 6) + ((((sl) ^ ((row) & 7))) << 3))

  // prologue: stage tile 0 fully, drain, barrier
  STG(As, Ab, 0, 0, 0); STG(As, Ab, 0, 1, 0);
  STG(Bs, Bb, 0, 0, 0); STG(Bs, Bb, 0, 1, 0);
  asm volatile("s_waitcnt vmcnt(0)" ::: "memory");
  __builtin_amdgcn_s_barrier();
  FENCE();

  bf16x8 af[4][2], bfr[4][2];

  for (int t = 0; t < 8; ++t) {
    const int cur = t & 1;
    const bool pre = (t < 7);
    // ---- P0: read A-half0 frags + B n0-1; stage A-h0,B-h0(t+1); MFMA m0-3 x n0-1
#pragma unroll
    for (int m = 0; m < 4; ++m)
#pragma unroll
      for (int kk = 0; kk < 2; ++kk) {
        int row = wr * 128 + m * 16 + fr;
        af[m][kk] = *reinterpret_cast<const bf16x8*>(&As[cur][LOFF(row, kk * 4 + fq)]);
      }
#pragma unroll
    for (int n = 0; n < 2; ++n)
#pragma unroll
      for (int kk = 0; kk < 2; ++kk) {
        int row = wc * 64 + n * 16 + fr;
        bfr[n][kk] = *reinterpret_cast<const bf16x8*>(&Bs[cur][LOFF(row, kk * 4 + fq)]);
      }
    if (pre) { STG(As, Ab, cur ^ 1, 0, t + 1); STG(Bs, Bb, cur ^ 1, 0, t + 1); }
    __builtin_amdgcn_s_setprio(1);
#pragma unroll
    for (int m = 0; m < 4; ++m)
#pragma unroll
      for (int n = 0; n < 2; ++n)
#pragma unroll
        for (int kk = 0; kk < 2; ++kk)
          acc[m][n] = __builtin_amdgcn_mfma_f32_16x16x32_bf16(af[m][kk], bfr[n][kk], acc[m][n], 0, 0, 0);
    __builtin_amdgcn_s_setprio(0);
    __builtin_amdgcn_s_barrier();
    FENCE();
    // ---- P1: read B n2-3; stage A-h1(t+1); MFMA m0-3 x n2-3
#pragma unroll
    for (int n = 0; n < 2; ++n)
#pragma unroll
      for (int kk = 0; kk < 2; ++kk) {
        int row = wc * 64 + (n + 2) * 16 + fr;
        bfr[n + 2][kk] = *reinterpret_cast<const bf16x8*>(&Bs[cur][LOFF(row, kk * 4 + fq)]);
      }
    if (pre) STG(As, Ab, cur ^ 1, 1, t + 1);
    __builtin_amdgcn_s_setprio(1);
#pragma unroll
    for (int m = 0; m < 4; ++m)
#pragma unroll
      for (int n = 0; n < 2; ++n)
#pragma unroll
        for (int kk = 0; kk < 2; ++kk)
          acc[m][n + 2] = __builtin_amdgcn_mfma_f32_16x16x32_bf16(af[m][kk], bfr[n + 2][kk], acc[m][n + 2], 0, 0, 0);
    __builtin_amdgcn_s_setprio(0);
    __builtin_amdgcn_s_barrier();
    FENCE();
    // ---- P2: read A-half1 frags (overwrite); stage B-h1(t+1); MFMA m4-7 x n0-1
#pragma unroll
    for (int m = 0; m < 4; ++m)
#pragma unroll
      for (int kk = 0; kk < 2; ++kk) {
        int row = wr * 128 + 64 + m * 16 + fr;
        af[m][kk] = *reinterpret_cast<const bf16x8*>(&As[cur][LOFF(row, kk * 4 + fq)]);
      }
    if (pre) STG(Bs, Bb, cur ^ 1, 1, t + 1);
    __builtin_amdgcn_s_setprio(1);
#pragma unroll
    for (int m = 0; m < 4; ++m)
#pragma unroll
      for (int n = 0; n < 2; ++n)
#pragma unroll
        for (int kk = 0; kk < 2; ++kk)
          acc[m + 4][n] = __builtin_amdgcn_mfma_f32_16x16x32_bf16(af[m][kk], bfr[n][kk], acc[m + 4][n], 0, 0, 0);
    __builtin_amdgcn_s_setprio(0);
    __builtin_amdgcn_s_barrier();
    FENCE();
    // ---- P3: MFMA m4-7 x n2-3; drain stages; boundary barrier
    __builtin_amdgcn_s_setprio(1);
#pragma unroll
    for (int m = 0; m < 4; ++m)
#pragma unroll
      for (int n = 0; n < 2; ++n)
#pragma unroll
        for (int kk = 0; kk < 2; ++kk)
          acc[m + 4][n + 2] = __builtin_amdgcn_mfma_f32_16x16x32_bf16(af[m][kk], bfr[n + 2][kk], acc[m + 4][n + 2], 0, 0, 0);
    __builtin_amdgcn_s_setprio(0);
    asm volatile("s_waitcnt vmcnt(0)" ::: "memory");
    __builtin_amdgcn_s_barrier();
    FENCE();
  }
#undef STG
#undef LOFF

  // ---- epilogue ----
  const int bm   = tm;
  const int head = tn * 4 + wc;
  float bj[4];
#pragma unroll
  for (int n = 0; n < 4; ++n) bj[n] = bias[tn * 256 + wc * 64 + n * 16 + fr];

  if (MODE == 0) {
    float cs[4] = {0.f, 0.f, 0.f, 0.f};
#pragma unroll
    for (int m = 0; m < 8; ++m) {
#pragma unroll
      for (int r = 0; r < 4; ++r) {
        float rs = 0.f;
#pragma unroll
        for (int n = 0; n < 4; ++n) {
          float v = elu1(acc[m][n][r] + bj[n]);
          rs += v;
          cs[n] += v;
        }
#pragma unroll
        for (int msk = 1; msk < 16; msk <<= 1) rs += __shfl_xor(rs, msk);
        if (fr == 0) {
          int tg = wr * 128 + m * 16 + fq * 4 + r;
          krow[((size_t)bm * NH + head) * T_ + tg] = rs;
        }
      }
    }
#pragma unroll
    for (int n = 0; n < 4; ++n) {
      cs[n] += __shfl_xor(cs[n], 16);
      cs[n] += __shfl_xor(cs[n], 32);
      if (fq == 0)
        ksum2[((size_t)wr * BM_ + bm) * C_ + tn * 256 + wc * 64 + n * 16 + fr] = cs[n];
    }
  } else {
    float ks[4];
#pragma unroll
    for (int n = 0; n < 4; ++n) {
      size_t col = (size_t)bm * C_ + tn * 256 + wc * 64 + n * 16 + fr;
      ks[n] = ksum2_in[col] + ksum2_in[(size_t)BM_ * C_ + col];
    }
#pragma unroll
    for (int m = 0; m < 8; ++m) {
#pragma unroll
      for (int r = 0; r < 4; ++r) {
        float zs = 0.f;
#pragma unroll
        for (int n = 0; n < 4; ++n) zs = fmaf(elu1(acc[m][n][r] + bj[n]), ks[n], zs);
#pragma unroll
        for (int msk = 1; msk < 16; msk <<= 1) zs += __shfl_xor(zs, msk);
        if (fr == 0) {
          int tg = wr * 128 + m * 16 + fq * 4 + r;
          zden[((size_t)bm * NH + head) * T_ + tg] = zs;
        }
      }
    }
  }
}

// xk4[q][bm,n,c] = sum_{t in quarter q} krow_n[t] * x[bm,t,c]; srow4 likewise.
__global__ __launch_bounds__(256) void xk_kernel(
    const unsigned short* __restrict__ xb, const float* __restrict__ krow,
    float* __restrict__ xk4, float* __restrict__ srow4)
{
  const int bm = blockIdx.x, qt = blockIdx.y, tid = threadIdx.x;
  __shared__ float krs[NH * 64];
#pragma unroll
  for (int p = 0; p < 2; ++p) {
    int idx = tid + p * 256;
    int n = idx >> 6, t = idx & 63;
    krs[idx] = krow[((size_t)bm * NH + n) * T_ + qt * 64 + t];
  }
  __syncthreads();
  float a0[8], a1[8];
#pragma unroll
  for (int n = 0; n < 8; ++n) { a0[n] = 0.f; a1[n] = 0.f; }
  const unsigned short* xp = xb + ((size_t)bm * T_ + qt * 64) * C_ + tid * 2;
  for (int t = 0; t < 64; ++t) {
    ushort2 u = *reinterpret_cast<const ushort2*>(xp + (size_t)t * C_);
    float x0 = bf2f(u.x), x1 = bf2f(u.y);
#pragma unroll
    for (int n = 0; n < 8; ++n) {
      float kr = krs[n * 64 + t];
      a0[n] = fmaf(kr, x0, a0[n]);
      a1[n] = fmaf(kr, x1, a1[n]);
    }
  }
#pragma unroll
  for (int n = 0; n < 8; ++n)
    *reinterpret_cast<float2*>(&xk4[(((size_t)qt * BM_ + bm) * NH + n) * C_ + tid * 2])
        = make_float2(a0[n], a1[n]);
  if (tid < 8) {
    float s = 0.f;
    for (int t = 0; t < 64; ++t) s += krs[tid * 64 + t];
    srow4[((size_t)qt * BM_ + bm) * NH + tid] = s;
  }
}

// colsum[bm,h,e] = Wv[h*64+e,:] . xk[bm,h,:] + srow[bm,h]*bv[h*64+e]
__global__ __launch_bounds__(256) void colsum_kernel(
    const float* __restrict__ xk4, const float* __restrict__ srow4,
    const float* __restrict__ Wv, const float* __restrict__ bv,
    float* __restrict__ cs_g)
{
  const int bm0 = blockIdx.x * 8, h = blockIdx.y, tid = threadIdx.x;
  __shared__ float4 xs4[8][128];
#pragma unroll
  for (int p = 0; p < 4; ++p) {
    int idx = tid + p * 256;
    int bmr = idx >> 7, c4 = idx & 127;
    float4 s = make_float4(0.f, 0.f, 0.f, 0.f);
#pragma unroll
    for (int q = 0; q < 4; ++q) {
      float4 u = *reinterpret_cast<const float4*>(
          xk4 + (((size_t)q * BM_ + bm0 + bmr) * NH + h) * C_ + c4 * 4);
      s.x += u.x; s.y += u.y; s.z += u.z; s.w += u.w;
    }
    xs4[bmr][c4] = s;
  }
  __syncthreads();
  const int e = tid & 63, bs = tid >> 6;
  const float4* wv4 = reinterpret_cast<const float4*>(Wv + (size_t)(h * DH + e) * C_);
  float acc0 = 0.f, acc1 = 0.f;
#pragma unroll 4
  for (int c4 = 0; c4 < 128; ++c4) {
    float4 w = wv4[c4];
    float4 a = xs4[bs * 2][c4];
    float4 b = xs4[bs * 2 + 1][c4];
    acc0 += w.x * a.x + w.y * a.y + w.z * a.z + w.w * a.w;
    acc1 += w.x * b.x + w.y * b.y + w.z * b.z + w.w * b.w;
  }
  float bve = bv[h * DH + e];
  int bmA = bm0 + bs * 2, bmB = bmA + 1;
  float sA = 0.f, sB = 0.f;
#pragma unroll
  for (int q = 0; q < 4; ++q) {
    sA += srow4[((size_t)q * BM_ + bmA) * NH + h];
    sB += srow4[((size_t)q * BM_ + bmB) * NH + h];
  }
  cs_g[((size_t)bmA * NH + h) * DH + e] = acc0 + sA * bve;
  cs_g[((size_t)bmB * NH + h) * DH + e] = acc1 + sB * bve;
}

// wbuf[bm,h,cp] = sum_e cs[bm,h,e] * Wp[cp, h*64+e]
__global__ __launch_bounds__(256) void wbuf_kernel(
    const float* __restrict__ cs_g, const float* __restrict__ Wp,
    float* __restrict__ wbuf)
{
  const int cpt = blockIdx.x, h = blockIdx.y, bm0 = blockIdx.z * 16;
  const int tid = threadIdx.x;
  __shared__ float4 csL4[16][16];
  {
    int bmr = tid >> 4, e4 = tid & 15;
    csL4[bmr][e4] = *reinterpret_cast<const float4*>(
        cs_g + ((size_t)(bm0 + bmr) * NH + h) * DH + e4 * 4);
  }
  __syncthreads();
  const int cp = cpt * 256 + tid;
  float4 wp[16];
  const float4* wpr = reinterpret_cast<const float4*>(Wp + (size_t)cp * C_ + h * DH);
#pragma unroll
  for (int e4 = 0; e4 < 16; ++e4) wp[e4] = wpr[e4];
#pragma unroll
  for (int bmr = 0; bmr < 16; ++bmr) {
    float acc = 0.f;
#pragma unroll
    for (int e4 = 0; e4 < 16; ++e4) {
      float4 c = csL4[bmr][e4];
      acc += wp[e4].x * c.x + wp[e4].y * c.y + wp[e4].z * c.z + wp[e4].w * c.w;
    }
    wbuf[((size_t)(bm0 + bmr) * NH + h) * C_ + cp] = acc;
  }
}

// out[bm,t,c'] = sum_n z_n[t]*w_n[c'] + bp[c'],  z = 1/(zden+eps)
__global__ __launch_bounds__(256) void out_kernel(
    const float* __restrict__ zden, const float* __restrict__ wbuf,
    const float* __restrict__ bp, float* __restrict__ out)
{
  const int bm = blockIdx.x, tt = blockIdx.y, tid = threadIdx.x;
  __shared__ float zs[NH][64];
#pragma unroll
  for (int p = 0; p < 2; ++p) {
    int idx = tid + p * 256;
    int n = idx >> 6, t = idx & 63;
    zs[n][t] = 1.f / (zden[((size_t)bm * NH + n) * T_ + tt * 64 + t] + 1e-6f);
  }
  float2 wv[8];
  const int c2 = tid * 2;
#pragma unroll
  for (int n = 0; n < 8; ++n)
    wv[n] = *reinterpret_cast<const float2*>(wbuf + ((size_t)bm * NH + n) * C_ + c2);
  float2 bpv = *reinterpret_cast<const float2*>(bp + c2);
  __syncthreads();
  float* ob = out + ((size_t)bm * T_ + tt * 64) * C_;
  for (int t = 0; t < 64; ++t) {
    float o0 = bpv.x, o1 = bpv.y;
#pragma unroll
    for (int n = 0; n < 8; ++n) { float z = zs[n][t]; o0 = fmaf(z, wv[n].x, o0); o1 = fmaf(z, wv[n].y, o1); }
    *reinterpret_cast<float2*>(ob + (size_t)t * C_ + c2) = make_float2(o0, o1);
  }
}

extern "C" void kernel_launch(void* const* d_in, const int* in_sizes, int n_in,
                              void* d_out, int out_size, void* d_ws, size_t ws_size,
                              hipStream_t stream)
{
  const float* x  = (const float*)d_in[0];
  const float* Wq = (const float*)d_in[1];
  const float* bq = (const float*)d_in[2];
  const float* Wk = (const float*)d_in[3];
  const float* bk = (const float*)d_in[4];
  const float* Wv = (const float*)d_in[5];
  const float* bv = (const float*)d_in[6];
  const float* Wp = (const float*)d_in[7];
  const float* bp = (const float*)d_in[8];
  float* out = (float*)d_out;

  float* ws    = (float*)d_ws;
  float* zden  = ws;                        // 262144 f
  float* ksum2 = zden + 262144;             // 2*128*512 = 131072 f
  float* krow  = ksum2 + 131072;            // 262144 f
  float* srow4 = krow + 262144;             // 4096 f
  float* xk4   = srow4 + 4096;              // 4*128*8*512 = 2097152 f
  float* cs    = xk4 + 2097152;             // 65536 f
  float* wbuf  = cs + 65536;                // 524288 f
  unsigned short* xb  = (unsigned short*)(wbuf + 524288);  // 16.7M bf16
  unsigned short* wkb = xb + 16777216;
  unsigned short* wqb = wkb + 262144;

  cvt3_kernel<<<2048, 256, 0, stream>>>(x, 16777216 / 4, Wk, 262144 / 4, Wq, 262144 / 4,
                                        xb, wkb, wqb);

  gemm_proj<0><<<256, 512, 0, stream>>>((const bf16*)xb, (const bf16*)wkb, bk,
                                        krow, ksum2, nullptr, nullptr);
  xk_kernel<<<dim3(BM_, 4), 256, 0, stream>>>(xb, krow, xk4, srow4);
  colsum_kernel<<<dim3(16, 8), 256, 0, stream>>>(xk4, srow4, Wv, bv, cs);
  wbuf_kernel<<<dim3(2, 8, 8), 256, 0, stream>>>(cs, Wp, wbuf);
  gemm_proj<1><<<256, 512, 0, stream>>>((const bf16*)xb, (const bf16*)wqb, bq,
                                        nullptr, nullptr, ksum2, zden);
  out_kernel<<<dim3(BM_, 4), 256, 0, stream>>>(zden, wbuf, bp, out);
}